// Round 15
// baseline (109.723 us; speedup 1.0000x reference)
//
#include <hip/hip_runtime.h>
#include <math.h>

typedef unsigned short u16;
typedef unsigned int u32;
typedef __attribute__((ext_vector_type(8))) __bf16 bf16x8;
typedef __attribute__((ext_vector_type(8))) u16 u16x8;
typedef __attribute__((ext_vector_type(4))) u16 u16x4;
typedef __attribute__((ext_vector_type(4))) u32 u32x4;
typedef __attribute__((ext_vector_type(4))) float f32x4;

#define GLOAD16(gp, lp)                                                        \
  __builtin_amdgcn_global_load_lds(                                            \
      (const __attribute__((address_space(1))) unsigned int*)(gp),             \
      (__attribute__((address_space(3))) unsigned int*)(lp), 16, 0, 0)

#define LOG2E 1.4426950408889634f

__device__ __forceinline__ u16 bf16r(float f) {
  unsigned u = __float_as_uint(f);
  u += 0x7fff + ((u >> 16) & 1);
  return (u16)(u >> 16);
}

__device__ __forceinline__ bf16x8 ldfrag(const u16* p) {
  return __builtin_bit_cast(bf16x8, *(const u16x8*)p);
}

__device__ __forceinline__ f32x4 mfma16(bf16x8 a, bf16x8 b, f32x4 c) {
  return __builtin_amdgcn_mfma_f32_16x16x32_bf16(a, b, c, 0, 0, 0);
}

__device__ __forceinline__ float fast_exp2(float x) {
  float r;
  asm("v_exp_f32 %0, %1" : "=v"(r) : "v"(x));
  return r;
}

// ---------------- constants ----------------
// B=2 S=2048 D_MODEL=1024 H=16 DKV=64, inner=1024
#define QKV_MAT_STRIDE (2 * 16 * 2048 * 64)  // elements per one of q/k/v

// ---------------- fused prep: transpose + rmsnorm + lut + wk --------------
// blocks [0,4096): weight transpose; [4096,8192): rmsnorm rows;
// [8192,8225): bucket LUT; [8225,8241): per-key weight wk.
__global__ __launch_bounds__(256) void k_prep(
    const float* __restrict__ hs, const float* __restrict__ lnw,
    u16* __restrict__ normed, const float* __restrict__ Wq,
    const float* __restrict__ Wk, const float* __restrict__ Wv,
    const float* __restrict__ Wo, u16* __restrict__ wtqkv,
    u16* __restrict__ wto, const float* __restrict__ mask,
    const float* __restrict__ ssc, const int* __restrict__ nd,
    float* __restrict__ wkf, u16* __restrict__ wkp,
    signed char* __restrict__ lut8) {
  const int blk = blockIdx.x, t = threadIdx.x;
  __shared__ float tile[32][33];
  __shared__ float wsum[4];

  if (blk < 4096) {  // ---- weight transpose fp32 [k][n] -> bf16 [n][k]
    int z = blk >> 10, rem = blk & 1023;
    int n0 = (rem & 31) * 32, k0 = (rem >> 5) * 32;
    const float* W = (z == 0) ? Wq : (z == 1) ? Wk : (z == 2) ? Wv : Wo;
    u16* Wt = (z < 3) ? (wtqkv + (size_t)z * 1024 * 1024) : wto;
    int tx = t & 31, ty = t >> 5;  // (32,8)
#pragma unroll
    for (int j = 0; j < 4; ++j)
      tile[ty + 8 * j][tx] = W[(size_t)(k0 + ty + 8 * j) * 1024 + n0 + tx];
    __syncthreads();
#pragma unroll
    for (int j = 0; j < 4; ++j)
      Wt[(size_t)(n0 + ty + 8 * j) * 1024 + k0 + tx] =
          bf16r(tile[tx][ty + 8 * j]);
  } else if (blk < 8192) {  // ---- RMSNorm row -> bf16
    int row = blk - 4096;
    const float4 v = ((const float4*)(hs + (size_t)row * 1024))[t];
    float ss = v.x * v.x + v.y * v.y + v.z * v.z + v.w * v.w;
#pragma unroll
    for (int o = 1; o < 64; o <<= 1) ss += __shfl_xor(ss, o);
    if ((t & 63) == 0) wsum[t >> 6] = ss;
    __syncthreads();
    float tot = wsum[0] + wsum[1] + wsum[2] + wsum[3];
    float rs = rsqrtf(tot * (1.0f / 1024.0f) + 1e-6f);
    const float4 wv = ((const float4*)lnw)[t];
    u16x4 o4;
    o4[0] = bf16r(v.x * rs * wv.x);
    o4[1] = bf16r(v.y * rs * wv.y);
    o4[2] = bf16r(v.z * rs * wv.z);
    o4[3] = bf16r(v.w * rs * wv.w);
    *(u16x4*)(normed + (size_t)row * 1024 + t * 4) = o4;
  } else if (blk < 8225) {  // ---- T5 bucket LUT, rel in [-4096,4096]
    int i = (blk - 8192) * 256 + t;
    if (i <= 8192) {
      int rel = i - 4096;
      int ret = rel > 0 ? 16 : 0;
      int n = rel < 0 ? -rel : rel;
      int bucket;
      if (n < 8) {
        bucket = n;
      } else {
        int vl = 8 + (int)(log((double)n / 8.0) / log(16.0) * 8.0);
        bucket = vl > 15 ? 15 : vl;
      }
      lut8[i] = (signed char)(ret + bucket);
    }
  } else {  // ---- wk = e^{-1000(1-m)}(ss+1e-4)(nd+1e-4); + slot-perm bf16
    int i = (blk - 8225) * 256 + t;  // < 4096
    float wv = __expf(-1000.0f * (1.0f - mask[i])) * (ssc[i] + 1e-4f) *
               ((float)nd[i] + 1e-4f);
    wkf[i] = wv;
    int o = i & 31;
    int slot = (o < 16) ? (o << 1) : (((o - 16) << 1) | 1);
    wkp[(i & ~31) | slot] = bf16r(wv);
  }
}

// ---------------- 128x128 bf16 MFMA GEMM, K=1024, 2-phase pipelined -------
// (R12 proven version: buffers are 8192 u16 = 16KB each — a 128x64 bf16
// tile.) K-loop: STAGE(next) -> compute(cur) -> vmcnt(0) -> s_barrier.
// mode 0 (768 blocks): z=0 -> q*log2e, z=1 -> k, both [bh][s][64];
//         z=2 -> v*wk transposed + slot-permuted to [bh][d][2048]
// mode 1 (256 blocks): out -> fp32 row-major d_out
// 1-D grid, XCD-swizzled decode: my=4*(i&7)+((i>>3)&3); nx=(i>>5)&7; z=i>>8.
__device__ __forceinline__ void gemm_step(const u16* __restrict__ As,
                                          const u16* __restrict__ Bs,
                                          int wr, int wc, int lane,
                                          f32x4 acc[4][4]) {
#pragma unroll
  for (int kk = 0; kk < 2; ++kk) {
    bf16x8 af[4], bfr[4];
#pragma unroll
    for (int mi = 0; mi < 4; ++mi) {
      int r = (wr << 6) + (mi << 4) + (lane & 15);
      int cb = ((kk << 6) + ((lane >> 4) << 4)) ^ ((r & 7) << 4);
      af[mi] = ldfrag(As + (((r << 7) + cb) >> 1));
    }
#pragma unroll
    for (int ni = 0; ni < 4; ++ni) {
      int r = (wc << 6) + (ni << 4) + (lane & 15);
      int cb = ((kk << 6) + ((lane >> 4) << 4)) ^ ((r & 7) << 4);
      bfr[ni] = ldfrag(Bs + (((r << 7) + cb) >> 1));
    }
#pragma unroll
    for (int mi = 0; mi < 4; ++mi)
#pragma unroll
      for (int ni = 0; ni < 4; ++ni)
        acc[mi][ni] = mfma16(af[mi], bfr[ni], acc[mi][ni]);
  }
}

__global__ __launch_bounds__(256) void k_gemm(const u16* __restrict__ A,
                                              const u16* __restrict__ Bt,
                                              u16* __restrict__ outB,
                                              float* __restrict__ outF,
                                              const float* __restrict__ wkf,
                                              int mode) {
  const int t = threadIdx.x, lane = t & 63, w = t >> 6;
  const int wr = w >> 1, wc = w & 1;
  const int bi0 = blockIdx.x;
  const int my = 4 * (bi0 & 7) + ((bi0 >> 3) & 3);
  const int nx = (bi0 >> 5) & 7;
  const int z = bi0 >> 8;
  const int m0 = my << 7, n0 = nx << 7;
  const u16* Btm = Bt + (size_t)z * (1024 * 1024);
  __shared__ alignas(16) u16 smem[32768];  // A0|A1|B0|B1 (16KB each); epilogue reuse
  u16* As0 = smem;
  u16* As1 = smem + 8192;
  u16* Bs0 = smem + 16384;
  u16* Bs1 = smem + 24576;

#define GSTAGE(ab, bb, k0)                                                   \
  do {                                                                       \
    _Pragma("unroll") for (int i = 0; i < 4; ++i) {                          \
      const int o = ((i * 4 + w) * 64 + lane) << 4;                          \
      const int r = o >> 7;                                                  \
      const int cb = (o & 127) ^ ((r & 7) << 4);                             \
      GLOAD16((const char*)A + (size_t)(m0 + r) * 2048 + ((k0) << 1) + cb,   \
              (char*)(ab) + (i * 4 + w) * 1024);                             \
      GLOAD16((const char*)Btm + (size_t)(n0 + r) * 2048 + ((k0) << 1) + cb, \
              (char*)(bb) + (i * 4 + w) * 1024);                             \
    }                                                                        \
  } while (0)

  f32x4 acc[4][4];
#pragma unroll
  for (int i = 0; i < 4; ++i)
#pragma unroll
    for (int j = 0; j < 4; ++j) acc[i][j] = (f32x4){0.f, 0.f, 0.f, 0.f};

  GSTAGE(As0, Bs0, 0);
  asm volatile("s_waitcnt vmcnt(0)" ::: "memory");
  __builtin_amdgcn_s_barrier();
  __builtin_amdgcn_sched_barrier(0);

  for (int k0 = 0; k0 < 1024; k0 += 128) {
    // phase A: prefetch tile k0+64 into buf1, compute buf0 (tile k0)
    GSTAGE(As1, Bs1, k0 + 64);
    gemm_step(As0, Bs0, wr, wc, lane, acc);
    asm volatile("s_waitcnt vmcnt(0)" ::: "memory");  // buf1 landed (hidden)
    __builtin_amdgcn_s_barrier();                     // all done reading buf0
    __builtin_amdgcn_sched_barrier(0);
    // phase B: prefetch tile k0+128 into buf0, compute buf1
    if (k0 + 128 < 1024) GSTAGE(As0, Bs0, k0 + 128);
    gemm_step(As1, Bs1, wr, wc, lane, acc);
    asm volatile("s_waitcnt vmcnt(0)" ::: "memory");
    __builtin_amdgcn_s_barrier();
    __builtin_amdgcn_sched_barrier(0);
  }
#undef GSTAGE

  const int rbase = (lane >> 4) << 2;
  const int cl = lane & 15;
  if (mode == 0) {
    u16* dst = outB + (size_t)z * QKV_MAT_STRIDE;
    if (z < 2) {
      // q/k: two 64-row passes via LDS [64][136] u16, coalesced 16B stores
      const float scl = (z == 0) ? LOG2E : 1.0f;
      const int bb = m0 >> 11;
#pragma unroll
      for (int pass = 0; pass < 2; ++pass) {
        if (pass) __syncthreads();
        if (wr == pass) {
#pragma unroll
          for (int mi = 0; mi < 4; ++mi)
#pragma unroll
            for (int ni = 0; ni < 4; ++ni)
#pragma unroll
              for (int i = 0; i < 4; ++i) {
                int r = (mi << 4) + rbase + i;               // 0..63
                int col = (wc << 6) + (ni << 4) + cl;        // 0..127
                smem[r * 136 + col] = bf16r(acc[mi][ni][i] * scl);
              }
        }
        __syncthreads();
#pragma unroll
        for (int j = 0; j < 4; ++j) {
          int e = t * 8 + j * 2048;   // 64 rows x 128 cols
          int r = e >> 7, c = e & 127;
          int s = (m0 & 2047) + pass * 64 + r;
          int cg = n0 + c;
          int hh = cg >> 6, d = cg & 63;
          u16x8 val = *(u16x8*)&smem[r * 136 + c];
          *(u16x8*)&dst[(((size_t)(bb * 16 + hh)) * 2048 + s) * 64 + d] = val;
        }
      }
    } else {
      // V: scale by wk, transpose via LDS, slot-permute s, coalesced out.
      const int s0 = m0 & 2047, bb = m0 >> 11;
#pragma unroll
      for (int h2 = 0; h2 < 2; ++h2) {
        if (h2) __syncthreads();
#pragma unroll
        for (int nb = 0; nb < 2; ++nb) {
          int ni = 2 * h2 + nb;
          int ld = wc * 32 + nb * 16 + cl;
#pragma unroll
          for (int mi = 0; mi < 4; ++mi)
#pragma unroll
            for (int i = 0; i < 4; ++i) {
              int sl = (wr << 6) + (mi << 4) + rbase + i;
              int o = sl & 31;
              int sp = (sl & ~31) | ((o < 16) ? (o << 1) : (((o - 16) << 1) | 1));
              smem[ld * 136 + sp] = bf16r(acc[mi][ni][i] * wkf[m0 + sl]);
            }
        }
        __syncthreads();
#pragma unroll
        for (int rr = 0; rr < 4; ++rr) {
          int ld = rr * 16 + (t >> 4);
          int cu = (t & 15) * 8;
          int cgo = ((ld >> 5) << 6) + ((2 * h2 + ((ld >> 4) & 1)) << 4) + (ld & 15);
          int cg = n0 + cgo;
          int hh = cg >> 6, d = cg & 63;
          u16x8 val = *(u16x8*)&smem[ld * 136 + cu];
          *(u16x8*)&dst[(((size_t)(bb * 16 + hh)) * 64 + d) * 2048 + s0 + cu] = val;
        }
      }
    }
  } else {
    // fp32 out: four 32-row passes via LDS [32][132] f32, coalesced 16B stores
    float* smemf = (float*)smem;
#pragma unroll
    for (int pass = 0; pass < 4; ++pass) {
      if (pass) __syncthreads();
      if (wr == (pass >> 1)) {
#pragma unroll
        for (int mh = 0; mh < 2; ++mh) {
          int mi = 2 * (pass & 1) + mh;
#pragma unroll
          for (int ni = 0; ni < 4; ++ni)
#pragma unroll
            for (int i = 0; i < 4; ++i) {
              int r = (mh << 4) + rbase + i;          // 0..31
              int col = (wc << 6) + (ni << 4) + cl;   // 0..127
              smemf[r * 132 + col] = acc[mi][ni][i];
            }
        }
      }
      __syncthreads();
#pragma unroll
      for (int j = 0; j < 4; ++j) {
        int e = t * 4 + j * 1024;  // 32 rows x 128 cols
        int r = e >> 7, c = e & 127;
        f32x4 val = *(f32x4*)&smemf[r * 132 + c];
        *(f32x4*)&outF[(size_t)(m0 + pass * 32 + r) * 1024 + n0 + c] = val;
      }
    }
  }
}

// ---------------- flash attention: swapped-QK, P in reg, T15 pipeline -----
// grid (32 bh, 16 qb); 256 thr = 4 waves x 32 q-rows, K/V chunks of 64.
// K ring of 2, V ring of 3 (49.9KB LDS -> 3 blocks/CU, 12 waves/CU).
// Two barriers/chunk: [vmcnt(4); bar] compute [bar] STAGE(i+2).
// Safety: STAGE(i+2) writes Ks[i&1] (last read by QK(i), pre-barrier) and
// Vs[(i+2)%3] == Vs[(i-1)%3] (last read by PV(i-1), pre-barrier). V(i+2) is
// next read at iter i+3; retired by vmcnt(4) at iter i+2's top.
__global__ __launch_bounds__(256) void k_attn(
    const u16* __restrict__ qkv, const int* __restrict__ positions,
    const signed char* __restrict__ lut8, const float* __restrict__ rel_emb,
    const u16* __restrict__ wkp, u16* __restrict__ ctx) {
  const int t = threadIdx.x, lane = t & 63, w = t >> 6;
  const int g = lane >> 4, c = lane & 15;
  const int bh = blockIdx.x, qb = blockIdx.y;
  const int b = bh >> 4, h = bh & 15;
  const size_t hb = (size_t)bh * (2048 * 64);
  const u16* Qg = qkv + hb + (size_t)qb * 128 * 64;
  const char* Kg = (const char*)(qkv + (size_t)QKV_MAT_STRIDE + hb);
  const char* Vg = (const char*)(qkv + (size_t)2 * QKV_MAT_STRIDE + hb);

  __shared__ alignas(16) u16 Ks[2][4096];  // K ring (8KB chunks)
  __shared__ alignas(16) u16 Vs[3][4096];  // V ring (8KB chunks)
  __shared__ alignas(16) u16 poss[2048];
  __shared__ alignas(16) u16 wkps[2048];
  __shared__ float lutf[192];  // bucket bias * log2e for rel in [-92,92]

  if (t < 185) lutf[t] = rel_emb[(int)lut8[t - 92 + 4096] * 16 + h] * LOG2E;
#pragma unroll
  for (int i = 0; i < 8; ++i) {
    poss[i * 256 + t] = (u16)positions[b * 2048 + i * 256 + t];
    wkps[i * 256 + t] = wkp[b * 2048 + i * 256 + t];
  }

  // Q as B-operand: lane (g,c) holds Q[q = w*32 + qh*16 + c][dims kk*32+g*8..]
  bf16x8 qa[2][2];
#pragma unroll
  for (int qh = 0; qh < 2; ++qh) {
    const u16* qrow = Qg + (size_t)(w * 32 + qh * 16 + c) * 64;
    qa[qh][0] = ldfrag(qrow + g * 8);
    qa[qh][1] = ldfrag(qrow + 32 + g * 8);
  }
  const int qrow0 = qb * 128 + w * 32;  // wave's first q row
  int npq[2];
  npq[0] = 92 - positions[b * 2048 + qrow0 + c];
  npq[1] = 92 - positions[b * 2048 + qrow0 + 16 + c];
  const int pqmin = positions[b * 2048 + qrow0];
  const int pqmax = positions[b * 2048 + qrow0 + 31];

  // staging (256 thr): K chunk 8KB = 2 calls (rows 0-31 / 32-63), V same.
  const int so = t << 4;
  const int sr = so >> 7;  // row 0..31
  const int scb = (so & 127) ^ ((sr & 7) << 4);
  const char* srcK0 = Kg + sr * 128 + scb;
  const char* srcK1 = Kg + (sr + 32) * 128 + scb;
  const char* srcV0 = Vg + sr * 4096 + scb;
  const char* srcV1 = Vg + (sr + 32) * 4096 + scb;

#define STAGE(kb, vb)                                    \
  do {                                                   \
    GLOAD16(srcK0, (char*)Ks[kb] + w * 1024);            \
    GLOAD16(srcK1, (char*)Ks[kb] + 4096 + w * 1024);     \
    GLOAD16(srcV0, (char*)Vs[vb] + w * 1024);            \
    GLOAD16(srcV1, (char*)Vs[vb] + 4096 + w * 1024);     \
    srcK0 += 8192; srcK1 += 8192;                        \
    srcV0 += 128;  srcV1 += 128;                         \
  } while (0)

  f32x4 oacc[2][4];
  f32x4 lacc[2];
#pragma unroll
  for (int qh = 0; qh < 2; ++qh) {
    lacc[qh] = (f32x4){0.f, 0.f, 0.f, 0.f};
#pragma unroll
    for (int i = 0; i < 4; ++i) oacc[qh][i] = (f32x4){0.f, 0.f, 0.f, 0.f};
  }
  bf16x8 pa_prev[2][2];  // P tile of previous chunk (PV deferred one iter)

  __syncthreads();  // LDS init visible
  STAGE(0, 0);
  STAGE(1, 1);
  const float lut_lo = lutf[0], lut_hi = lutf[184];

  for (int i2 = 0; i2 < 32; ++i2) {
    // in flight at wait: stage(i2) [maybe retired] + stage(i2+1) -> vmcnt(4)
    // guarantees chunk-i2 loads retired; barrier makes it block-wide.
    if (i2 < 31)
      asm volatile("s_waitcnt vmcnt(4)" ::: "memory");
    else
      asm volatile("s_waitcnt vmcnt(0)" ::: "memory");
    __builtin_amdgcn_s_barrier();
    __builtin_amdgcn_sched_barrier(0);

    const u16* ksb = Ks[i2 & 1];
    const int kc = i2 << 6;

    // S = K Q (swapped): sc[sub][qh] = P[key kc+sub*16+g*4+i][q=qh*16+c]
    f32x4 sc[4][2];
    __builtin_amdgcn_s_setprio(1);
#pragma unroll
    for (int sub = 0; sub < 4; ++sub) {
      int r = sub * 16 + c;
      int cb0 = (g << 4) ^ ((r & 7) << 4);
      int cb1 = (64 + (g << 4)) ^ ((r & 7) << 4);
      bf16x8 kf0 = ldfrag(ksb + (((r << 7) + cb0) >> 1));
      bf16x8 kf1 = ldfrag(ksb + (((r << 7) + cb1) >> 1));
#pragma unroll
      for (int qh = 0; qh < 2; ++qh) {
        f32x4 a = (f32x4){0.f, 0.f, 0.f, 0.f};
        a = mfma16(kf0, qa[qh][0], a);
        a = mfma16(kf1, qa[qh][1], a);
        sc[sub][qh] = a;
      }
    }
    __builtin_amdgcn_s_setprio(0);

    // ---- PV of PREVIOUS chunk (MFMA pipe) -- independent of exp below ----
    if (i2 > 0) {
      const u16* vsb = Vs[(i2 - 1) % 3];
      const int kcp = kc - 64;
      __builtin_amdgcn_s_setprio(1);
#pragma unroll
      for (int kk = 0; kk < 2; ++kk) {
        bf16x8 wkf2 = ldfrag(wkps + kcp + kk * 32 + g * 8);
        bf16x8 vf[4];
#pragma unroll
        for (int d2 = 0; d2 < 4; ++d2) {
          int vr = d2 * 16 + c;
          int vcb = ((kk << 6) + (g << 4)) ^ ((vr & 7) << 4);
          vf[d2] = ldfrag(vsb + (((vr << 7) + vcb) >> 1));
        }
#pragma unroll
        for (int qh = 0; qh < 2; ++qh) {
          lacc[qh] = mfma16(pa_prev[qh][kk], wkf2, lacc[qh]);
#pragma unroll
          for (int d2 = 0; d2 < 4; ++d2)
            oacc[qh][d2] = mfma16(pa_prev[qh][kk], vf[d2], oacc[qh][d2]);
        }
      }
      __builtin_amdgcn_s_setprio(0);
    }

    // ---- bias + exp2 of CURRENT chunk (VALU/trans pipe) ----
    int pkmin = (int)poss[kc];
    int pkmax = (int)poss[kc + 63];
    if ((pkmin - pqmax >= 92) || (pqmin - pkmax >= 92)) {
      float rbc = (pkmin - pqmax >= 92) ? lut_hi : lut_lo;
#pragma unroll
      for (int sub = 0; sub < 4; ++sub)
#pragma unroll
        for (int qh = 0; qh < 2; ++qh)
#pragma unroll
          for (int i = 0; i < 4; ++i)
            sc[sub][qh][i] = fast_exp2(sc[sub][qh][i] + rbc);
    } else {
#pragma unroll
      for (int sub = 0; sub < 4; ++sub) {
        u16x4 pk4 = *(const u16x4*)&poss[kc + sub * 16 + (g << 2)];
#pragma unroll
        for (int qh = 0; qh < 2; ++qh)
#pragma unroll
          for (int i = 0; i < 4; ++i) {
            int idx = (int)pk4[i] + npq[qh];
            idx = idx < 0 ? 0 : (idx > 184 ? 184 : idx);
            sc[sub][qh][i] = fast_exp2(sc[sub][qh][i] + lutf[idx]);
          }
      }
    }

    // P -> PV A-frags in registers: slot 2m <- sub 2kk, slot 2m+1 <- 2kk+1
#pragma unroll
    for (int qh = 0; qh < 2; ++qh)
#pragma unroll
      for (int kk = 0; kk < 2; ++kk) {
        u32x4 pw;
#pragma unroll
        for (int m = 0; m < 4; ++m) {
          u32 pr;
          asm("v_cvt_pk_bf16_f32 %0, %1, %2"
              : "=v"(pr)
              : "v"(sc[2 * kk][qh][m]), "v"(sc[2 * kk + 1][qh][m]));
          pw[m] = pr;
        }
        pa_prev[qh][kk] = __builtin_bit_cast(bf16x8, pw);
      }

    // ---- end-of-iter: free the recycled slots, then stage chunk i2+2 ----
    __builtin_amdgcn_s_barrier();  // all reads of Ks[i2&1], Vs[(i2-1)%3] done
    if (i2 < 30) STAGE(i2 & 1, (i2 + 2) % 3);
  }
#undef STAGE

  // epilogue: PV of the final chunk (31), Vs slot 31%3 = 1
  {
    const u16* vsb = Vs[31 % 3];
    const int kcp = 31 << 6;
#pragma unroll
    for (int kk = 0; kk < 2; ++kk) {
      bf16x8 wkf2 = ldfrag(wkps + kcp + kk * 32 + g * 8);
#pragma unroll
      for (int qh = 0; qh < 2; ++qh)
        lacc[qh] = mfma16(pa_prev[qh][kk], wkf2, lacc[qh]);
#pragma unroll
      for (int d2 = 0; d2 < 4; ++d2) {
        int vr = d2 * 16 + c;
        int vcb = ((kk << 6) + (g << 4)) ^ ((vr & 7) << 4);
        bf16x8 vf = ldfrag(vsb + (((vr << 7) + vcb) >> 1));
#pragma unroll
        for (int qh = 0; qh < 2; ++qh)
          oacc[qh][d2] = mfma16(pa_prev[qh][kk], vf, oacc[qh][d2]);
      }
    }
  }

#pragma unroll
  for (int qh = 0; qh < 2; ++qh)
#pragma unroll
    for (int i = 0; i < 4; ++i) {
      float iv = 1.0f / lacc[qh][i];
      int q = qrow0 + qh * 16 + (g << 2) + i;
#pragma unroll
      for (int d2 = 0; d2 < 4; ++d2)
        ctx[((size_t)b * 2048 + q) * 1024 + h * 64 + d2 * 16 + c] =
            bf16r(oacc[qh][d2][i] * iv);
    }
}

// ---------------- launch ----------------
extern "C" void kernel_launch(void* const* d_in, const int* in_sizes, int n_in,
                              void* d_out, int out_size, void* d_ws, size_t ws_size,
                              hipStream_t stream) {
  const float* hs = (const float*)d_in[0];
  const int* pos = (const int*)d_in[1];
  const float* mask = (const float*)d_in[2];
  const float* ss = (const float*)d_in[3];
  const int* nd = (const int*)d_in[4];
  const float* lnw = (const float*)d_in[5];
  const float* Wq = (const float*)d_in[6];
  const float* Wk = (const float*)d_in[7];
  const float* Wv = (const float*)d_in[8];
  const float* Wo = (const float*)d_in[9];
  const float* rel = (const float*)d_in[10];

  char* ws = (char*)d_ws;
  signed char* lut8 = (signed char*)ws;  //          0 .. 8448
  float* wkf = (float*)(ws + 8448);      //       8448 .. 24832
  u16* wkp = (u16*)(ws + 24832);         //      24832 .. 33024
  u16* normed = (u16*)(ws + 33024);      //    33024 + 8 MB (reused as ctx)
  u16* wtqkv = (u16*)(ws + 8421632);     //  + 6 MB
  u16* wto = (u16*)(ws + 14713088);      //  + 2 MB
  u16* qkv = (u16*)(ws + 16810240);      //  + 24 MB  (end 41976064)
  u16* ctx = normed;  // normed is dead after the QKV GEMM
  if (ws_size < 41976064) return;  // loud failure instead of corruption

  k_prep<<<8241, 256, 0, stream>>>(hs, lnw, normed, Wq, Wk, Wv, Wo, wtqkv,
                                   wto, mask, ss, nd, wkf, wkp, lut8);
  k_gemm<<<768, 256, 0, stream>>>(normed, wtqkv, qkv, nullptr, wkf, 0);
  k_attn<<<dim3(32, 16), 256, 0, stream>>>(qkv, pos, lut8, rel, wkp, ctx);
  k_gemm<<<256, 256, 0, stream>>>(ctx, wto, nullptr, (float*)d_out, wkf, 1);
}

// Round 16
// 107.006 us; speedup vs baseline: 1.0254x; 1.0254x over previous
//
#include <hip/hip_runtime.h>
#include <math.h>

typedef unsigned short u16;
typedef unsigned int u32;
typedef __attribute__((ext_vector_type(8))) __bf16 bf16x8;
typedef __attribute__((ext_vector_type(8))) u16 u16x8;
typedef __attribute__((ext_vector_type(4))) u16 u16x4;
typedef __attribute__((ext_vector_type(4))) u32 u32x4;
typedef __attribute__((ext_vector_type(4))) float f32x4;

#define GLOAD16(gp, lp)                                                        \
  __builtin_amdgcn_global_load_lds(                                            \
      (const __attribute__((address_space(1))) unsigned int*)(gp),             \
      (__attribute__((address_space(3))) unsigned int*)(lp), 16, 0, 0)

#define LOG2E 1.4426950408889634f

__device__ __forceinline__ u16 bf16r(float f) {
  unsigned u = __float_as_uint(f);
  u += 0x7fff + ((u >> 16) & 1);
  return (u16)(u >> 16);
}

__device__ __forceinline__ bf16x8 ldfrag(const u16* p) {
  return __builtin_bit_cast(bf16x8, *(const u16x8*)p);
}

__device__ __forceinline__ f32x4 mfma16(bf16x8 a, bf16x8 b, f32x4 c) {
  return __builtin_amdgcn_mfma_f32_16x16x32_bf16(a, b, c, 0, 0, 0);
}

__device__ __forceinline__ float fast_exp2(float x) {
  float r;
  asm("v_exp_f32 %0, %1" : "=v"(r) : "v"(x));
  return r;
}

// ---------------- constants ----------------
// B=2 S=2048 D_MODEL=1024 H=16 DKV=64, inner=1024
#define QKV_MAT_STRIDE (2 * 16 * 2048 * 64)  // elements per one of q/k/v

// ---------------- fused prep: transpose + rmsnorm + lut + wk --------------
// blocks [0,4096): weight transpose; [4096,8192): rmsnorm rows;
// [8192,8225): bucket LUT; [8225,8241): per-key weight wk.
__global__ __launch_bounds__(256) void k_prep(
    const float* __restrict__ hs, const float* __restrict__ lnw,
    u16* __restrict__ normed, const float* __restrict__ Wq,
    const float* __restrict__ Wk, const float* __restrict__ Wv,
    const float* __restrict__ Wo, u16* __restrict__ wtqkv,
    u16* __restrict__ wto, const float* __restrict__ mask,
    const float* __restrict__ ssc, const int* __restrict__ nd,
    float* __restrict__ wkf, u16* __restrict__ wkp,
    signed char* __restrict__ lut8) {
  const int blk = blockIdx.x, t = threadIdx.x;
  __shared__ float tile[32][33];
  __shared__ float wsum[4];

  if (blk < 4096) {  // ---- weight transpose fp32 [k][n] -> bf16 [n][k]
    int z = blk >> 10, rem = blk & 1023;
    int n0 = (rem & 31) * 32, k0 = (rem >> 5) * 32;
    const float* W = (z == 0) ? Wq : (z == 1) ? Wk : (z == 2) ? Wv : Wo;
    u16* Wt = (z < 3) ? (wtqkv + (size_t)z * 1024 * 1024) : wto;
    int tx = t & 31, ty = t >> 5;  // (32,8)
#pragma unroll
    for (int j = 0; j < 4; ++j)
      tile[ty + 8 * j][tx] = W[(size_t)(k0 + ty + 8 * j) * 1024 + n0 + tx];
    __syncthreads();
#pragma unroll
    for (int j = 0; j < 4; ++j)
      Wt[(size_t)(n0 + ty + 8 * j) * 1024 + k0 + tx] =
          bf16r(tile[tx][ty + 8 * j]);
  } else if (blk < 8192) {  // ---- RMSNorm row -> bf16
    int row = blk - 4096;
    const float4 v = ((const float4*)(hs + (size_t)row * 1024))[t];
    float ss = v.x * v.x + v.y * v.y + v.z * v.z + v.w * v.w;
#pragma unroll
    for (int o = 1; o < 64; o <<= 1) ss += __shfl_xor(ss, o);
    if ((t & 63) == 0) wsum[t >> 6] = ss;
    __syncthreads();
    float tot = wsum[0] + wsum[1] + wsum[2] + wsum[3];
    float rs = rsqrtf(tot * (1.0f / 1024.0f) + 1e-6f);
    const float4 wv = ((const float4*)lnw)[t];
    u16x4 o4;
    o4[0] = bf16r(v.x * rs * wv.x);
    o4[1] = bf16r(v.y * rs * wv.y);
    o4[2] = bf16r(v.z * rs * wv.z);
    o4[3] = bf16r(v.w * rs * wv.w);
    *(u16x4*)(normed + (size_t)row * 1024 + t * 4) = o4;
  } else if (blk < 8225) {  // ---- T5 bucket LUT, rel in [-4096,4096]
    int i = (blk - 8192) * 256 + t;
    if (i <= 8192) {
      int rel = i - 4096;
      int ret = rel > 0 ? 16 : 0;
      int n = rel < 0 ? -rel : rel;
      int bucket;
      if (n < 8) {
        bucket = n;
      } else {
        int vl = 8 + (int)(log((double)n / 8.0) / log(16.0) * 8.0);
        bucket = vl > 15 ? 15 : vl;
      }
      lut8[i] = (signed char)(ret + bucket);
    }
  } else {  // ---- wk = e^{-1000(1-m)}(ss+1e-4)(nd+1e-4); + slot-perm bf16
    int i = (blk - 8225) * 256 + t;  // < 4096
    float wv = __expf(-1000.0f * (1.0f - mask[i])) * (ssc[i] + 1e-4f) *
               ((float)nd[i] + 1e-4f);
    wkf[i] = wv;
    int o = i & 31;
    int slot = (o < 16) ? (o << 1) : (((o - 16) << 1) | 1);
    wkp[(i & ~31) | slot] = bf16r(wv);
  }
}

// ---------------- 128x128 bf16 MFMA GEMM, K=1024, 2-phase pipelined -------
// K-loop: STAGE(next) -> compute(cur) -> vmcnt(0) -> s_barrier. Load latency
// hides under the 64-MFMA compute phase.
// mode 0 (768 blocks): z=0 -> q*log2e, z=1 -> k, both [bh][s][64];
//         z=2 -> v*wk transposed + slot-permuted to [bh][d][2048]
// mode 1 (256 blocks): out -> fp32 row-major d_out
// 1-D grid, XCD-swizzled decode: my=4*(i&7)+((i>>3)&3); nx=(i>>5)&7; z=i>>8.
__device__ __forceinline__ void gemm_step(const u16* __restrict__ As,
                                          const u16* __restrict__ Bs,
                                          int wr, int wc, int lane,
                                          f32x4 acc[4][4]) {
#pragma unroll
  for (int kk = 0; kk < 2; ++kk) {
    bf16x8 af[4], bfr[4];
#pragma unroll
    for (int mi = 0; mi < 4; ++mi) {
      int r = (wr << 6) + (mi << 4) + (lane & 15);
      int cb = ((kk << 6) + ((lane >> 4) << 4)) ^ ((r & 7) << 4);
      af[mi] = ldfrag(As + (((r << 7) + cb) >> 1));
    }
#pragma unroll
    for (int ni = 0; ni < 4; ++ni) {
      int r = (wc << 6) + (ni << 4) + (lane & 15);
      int cb = ((kk << 6) + ((lane >> 4) << 4)) ^ ((r & 7) << 4);
      bfr[ni] = ldfrag(Bs + (((r << 7) + cb) >> 1));
    }
#pragma unroll
    for (int mi = 0; mi < 4; ++mi)
#pragma unroll
      for (int ni = 0; ni < 4; ++ni)
        acc[mi][ni] = mfma16(af[mi], bfr[ni], acc[mi][ni]);
  }
}

__global__ __launch_bounds__(256) void k_gemm(const u16* __restrict__ A,
                                              const u16* __restrict__ Bt,
                                              u16* __restrict__ outB,
                                              float* __restrict__ outF,
                                              const float* __restrict__ wkf,
                                              int mode) {
  const int t = threadIdx.x, lane = t & 63, w = t >> 6;
  const int wr = w >> 1, wc = w & 1;
  const int bi0 = blockIdx.x;
  const int my = 4 * (bi0 & 7) + ((bi0 >> 3) & 3);
  const int nx = (bi0 >> 5) & 7;
  const int z = bi0 >> 8;
  const int m0 = my << 7, n0 = nx << 7;
  const u16* Btm = Bt + (size_t)z * (1024 * 1024);
  __shared__ alignas(16) u16 smem[32768];  // A0|A1|B0|B1 (16KB each); epilogue reuse
  u16* As0 = smem;
  u16* As1 = smem + 8192;
  u16* Bs0 = smem + 16384;
  u16* Bs1 = smem + 24576;

#define GSTAGE(ab, bb, k0)                                                   \
  do {                                                                       \
    _Pragma("unroll") for (int i = 0; i < 4; ++i) {                          \
      const int o = ((i * 4 + w) * 64 + lane) << 4;                          \
      const int r = o >> 7;                                                  \
      const int cb = (o & 127) ^ ((r & 7) << 4);                             \
      GLOAD16((const char*)A + (size_t)(m0 + r) * 2048 + ((k0) << 1) + cb,   \
              (char*)(ab) + (i * 4 + w) * 1024);                             \
      GLOAD16((const char*)Btm + (size_t)(n0 + r) * 2048 + ((k0) << 1) + cb, \
              (char*)(bb) + (i * 4 + w) * 1024);                             \
    }                                                                        \
  } while (0)

  f32x4 acc[4][4];
#pragma unroll
  for (int i = 0; i < 4; ++i)
#pragma unroll
    for (int j = 0; j < 4; ++j) acc[i][j] = (f32x4){0.f, 0.f, 0.f, 0.f};

  GSTAGE(As0, Bs0, 0);
  asm volatile("s_waitcnt vmcnt(0)" ::: "memory");
  __builtin_amdgcn_s_barrier();
  __builtin_amdgcn_sched_barrier(0);

  for (int k0 = 0; k0 < 1024; k0 += 128) {
    // phase A: prefetch tile k0+64 into buf1, compute buf0 (tile k0)
    GSTAGE(As1, Bs1, k0 + 64);
    gemm_step(As0, Bs0, wr, wc, lane, acc);
    asm volatile("s_waitcnt vmcnt(0)" ::: "memory");  // buf1 landed (hidden)
    __builtin_amdgcn_s_barrier();                     // all done reading buf0
    __builtin_amdgcn_sched_barrier(0);
    // phase B: prefetch tile k0+128 into buf0, compute buf1
    if (k0 + 128 < 1024) GSTAGE(As0, Bs0, k0 + 128);
    gemm_step(As1, Bs1, wr, wc, lane, acc);
    asm volatile("s_waitcnt vmcnt(0)" ::: "memory");
    __builtin_amdgcn_s_barrier();
    __builtin_amdgcn_sched_barrier(0);
  }
#undef GSTAGE

  const int rbase = (lane >> 4) << 2;
  const int cl = lane & 15;
  if (mode == 0) {
    u16* dst = outB + (size_t)z * QKV_MAT_STRIDE;
    if (z < 2) {
      // q/k: two 64-row passes via LDS [64][136] u16, coalesced 16B stores
      const float scl = (z == 0) ? LOG2E : 1.0f;
      const int bb = m0 >> 11;
#pragma unroll
      for (int pass = 0; pass < 2; ++pass) {
        if (pass) __syncthreads();
        if (wr == pass) {
#pragma unroll
          for (int mi = 0; mi < 4; ++mi)
#pragma unroll
            for (int ni = 0; ni < 4; ++ni)
#pragma unroll
              for (int i = 0; i < 4; ++i) {
                int r = (mi << 4) + rbase + i;               // 0..63
                int col = (wc << 6) + (ni << 4) + cl;        // 0..127
                smem[r * 136 + col] = bf16r(acc[mi][ni][i] * scl);
              }
        }
        __syncthreads();
#pragma unroll
        for (int j = 0; j < 4; ++j) {
          int e = t * 8 + j * 2048;   // 64 rows x 128 cols
          int r = e >> 7, c = e & 127;
          int s = (m0 & 2047) + pass * 64 + r;
          int cg = n0 + c;
          int hh = cg >> 6, d = cg & 63;
          u16x8 val = *(u16x8*)&smem[r * 136 + c];
          *(u16x8*)&dst[(((size_t)(bb * 16 + hh)) * 2048 + s) * 64 + d] = val;
        }
      }
    } else {
      // V: scale by wk, transpose via LDS, slot-permute s, coalesced out.
      const int s0 = m0 & 2047, bb = m0 >> 11;
#pragma unroll
      for (int h2 = 0; h2 < 2; ++h2) {
        if (h2) __syncthreads();
#pragma unroll
        for (int nb = 0; nb < 2; ++nb) {
          int ni = 2 * h2 + nb;
          int ld = wc * 32 + nb * 16 + cl;
#pragma unroll
          for (int mi = 0; mi < 4; ++mi)
#pragma unroll
            for (int i = 0; i < 4; ++i) {
              int sl = (wr << 6) + (mi << 4) + rbase + i;
              int o = sl & 31;
              int sp = (sl & ~31) | ((o < 16) ? (o << 1) : (((o - 16) << 1) | 1));
              smem[ld * 136 + sp] = bf16r(acc[mi][ni][i] * wkf[m0 + sl]);
            }
        }
        __syncthreads();
#pragma unroll
        for (int rr = 0; rr < 4; ++rr) {
          int ld = rr * 16 + (t >> 4);
          int cu = (t & 15) * 8;
          int cgo = ((ld >> 5) << 6) + ((2 * h2 + ((ld >> 4) & 1)) << 4) + (ld & 15);
          int cg = n0 + cgo;
          int hh = cg >> 6, d = cg & 63;
          u16x8 val = *(u16x8*)&smem[ld * 136 + cu];
          *(u16x8*)&dst[(((size_t)(bb * 16 + hh)) * 64 + d) * 2048 + s0 + cu] = val;
        }
      }
    }
  } else {
    // fp32 out: four 32-row passes via LDS [32][132] f32, coalesced 16B stores
    float* smemf = (float*)smem;
#pragma unroll
    for (int pass = 0; pass < 4; ++pass) {
      if (pass) __syncthreads();
      if (wr == (pass >> 1)) {
#pragma unroll
        for (int mh = 0; mh < 2; ++mh) {
          int mi = 2 * (pass & 1) + mh;
#pragma unroll
          for (int ni = 0; ni < 4; ++ni)
#pragma unroll
            for (int i = 0; i < 4; ++i) {
              int r = (mh << 4) + rbase + i;          // 0..31
              int col = (wc << 6) + (ni << 4) + cl;   // 0..127
              smemf[r * 132 + col] = acc[mi][ni][i];
            }
        }
      }
      __syncthreads();
#pragma unroll
      for (int j = 0; j < 4; ++j) {
        int e = t * 4 + j * 1024;  // 32 rows x 128 cols
        int r = e >> 7, c = e & 127;
        f32x4 val = *(f32x4*)&smemf[r * 132 + c];
        *(f32x4*)&outF[(size_t)(m0 + pass * 32 + r) * 1024 + n0 + c] = val;
      }
    }
  }
}

// ---------------- flash attention: swapped-QK, P in reg, T15 pipeline -----
// grid (32 bh, 16 qb); 256 thr = 4 waves x 32 q-rows, K/V chunks of 64.
// K ring of 3, V ring of 4; PV of chunk i-1 runs inside iteration i.
__global__ __launch_bounds__(256) void k_attn(
    const u16* __restrict__ qkv, const int* __restrict__ positions,
    const signed char* __restrict__ lut8, const float* __restrict__ rel_emb,
    const u16* __restrict__ wkp, u16* __restrict__ ctx) {
  const int t = threadIdx.x, lane = t & 63, w = t >> 6;
  const int g = lane >> 4, c = lane & 15;
  const int bh = blockIdx.x, qb = blockIdx.y;
  const int b = bh >> 4, h = bh & 15;
  const size_t hb = (size_t)bh * (2048 * 64);
  const u16* Qg = qkv + hb + (size_t)qb * 128 * 64;
  const char* Kg = (const char*)(qkv + (size_t)QKV_MAT_STRIDE + hb);
  const char* Vg = (const char*)(qkv + (size_t)2 * QKV_MAT_STRIDE + hb);

  __shared__ alignas(16) u16 Ks[3][4096];  // K ring (8KB chunks)
  __shared__ alignas(16) u16 Vs[4][4096];  // V ring (8KB chunks)
  __shared__ alignas(16) u16 poss[2048];
  __shared__ alignas(16) u16 wkps[2048];
  __shared__ float lutf[192];  // bucket bias * log2e for rel in [-92,92]

  if (t < 185) lutf[t] = rel_emb[(int)lut8[t - 92 + 4096] * 16 + h] * LOG2E;
#pragma unroll
  for (int i = 0; i < 8; ++i) {
    poss[i * 256 + t] = (u16)positions[b * 2048 + i * 256 + t];
    wkps[i * 256 + t] = wkp[b * 2048 + i * 256 + t];
  }

  // Q as B-operand: lane (g,c) holds Q[q = w*32 + qh*16 + c][dims kk*32+g*8..]
  bf16x8 qa[2][2];
#pragma unroll
  for (int qh = 0; qh < 2; ++qh) {
    const u16* qrow = Qg + (size_t)(w * 32 + qh * 16 + c) * 64;
    qa[qh][0] = ldfrag(qrow + g * 8);
    qa[qh][1] = ldfrag(qrow + 32 + g * 8);
  }
  const int qrow0 = qb * 128 + w * 32;  // wave's first q row
  int npq[2];
  npq[0] = 92 - positions[b * 2048 + qrow0 + c];
  npq[1] = 92 - positions[b * 2048 + qrow0 + 16 + c];
  const int pqmin = positions[b * 2048 + qrow0];
  const int pqmax = positions[b * 2048 + qrow0 + 31];

  // staging (256 thr): K chunk 8KB = 2 calls (rows 0-31 / 32-63), V same.
  const int so = t << 4;
  const int sr = so >> 7;  // row 0..31
  const int scb = (so & 127) ^ ((sr & 7) << 4);
  const char* srcK0 = Kg + sr * 128 + scb;
  const char* srcK1 = Kg + (sr + 32) * 128 + scb;
  const char* srcV0 = Vg + sr * 4096 + scb;
  const char* srcV1 = Vg + (sr + 32) * 4096 + scb;

#define STAGE(kb, vb)                                    \
  do {                                                   \
    GLOAD16(srcK0, (char*)Ks[kb] + w * 1024);            \
    GLOAD16(srcK1, (char*)Ks[kb] + 4096 + w * 1024);     \
    GLOAD16(srcV0, (char*)Vs[vb] + w * 1024);            \
    GLOAD16(srcV1, (char*)Vs[vb] + 4096 + w * 1024);     \
    srcK0 += 8192; srcK1 += 8192;                        \
    srcV0 += 128;  srcV1 += 128;                         \
  } while (0)

  f32x4 oacc[2][4];
  f32x4 lacc[2];
#pragma unroll
  for (int qh = 0; qh < 2; ++qh) {
    lacc[qh] = (f32x4){0.f, 0.f, 0.f, 0.f};
#pragma unroll
    for (int i = 0; i < 4; ++i) oacc[qh][i] = (f32x4){0.f, 0.f, 0.f, 0.f};
  }
  bf16x8 pa_prev[2][2];  // P tile of previous chunk (PV deferred one iter)

  __syncthreads();  // LDS init visible
  STAGE(0, 0);
  STAGE(1, 1);
  const float lut_lo = lutf[0], lut_hi = lutf[184];

  for (int i2 = 0; i2 < 32; ++i2) {
    if (i2 < 31)
      asm volatile("s_waitcnt vmcnt(4)" ::: "memory");
    else
      asm volatile("s_waitcnt vmcnt(0)" ::: "memory");
    __builtin_amdgcn_s_barrier();
    __builtin_amdgcn_sched_barrier(0);
    if (i2 < 30) STAGE((i2 + 2) % 3, (i2 + 2) & 3);

    const u16* ksb = Ks[i2 % 3];
    const int kc = i2 << 6;

    // S = K Q (swapped): sc[sub][qh] = P[key kc+sub*16+g*4+i][q=qh*16+c]
    f32x4 sc[4][2];
    __builtin_amdgcn_s_setprio(1);
#pragma unroll
    for (int sub = 0; sub < 4; ++sub) {
      int r = sub * 16 + c;
      int cb0 = (g << 4) ^ ((r & 7) << 4);
      int cb1 = (64 + (g << 4)) ^ ((r & 7) << 4);
      bf16x8 kf0 = ldfrag(ksb + (((r << 7) + cb0) >> 1));
      bf16x8 kf1 = ldfrag(ksb + (((r << 7) + cb1) >> 1));
#pragma unroll
      for (int qh = 0; qh < 2; ++qh) {
        f32x4 a = (f32x4){0.f, 0.f, 0.f, 0.f};
        a = mfma16(kf0, qa[qh][0], a);
        a = mfma16(kf1, qa[qh][1], a);
        sc[sub][qh] = a;
      }
    }
    __builtin_amdgcn_s_setprio(0);

    // ---- PV of PREVIOUS chunk (MFMA pipe) -- independent of exp below ----
    if (i2 > 0) {
      const u16* vsb = Vs[(i2 - 1) & 3];
      const int kcp = kc - 64;
      __builtin_amdgcn_s_setprio(1);
#pragma unroll
      for (int kk = 0; kk < 2; ++kk) {
        bf16x8 wkf2 = ldfrag(wkps + kcp + kk * 32 + g * 8);
        bf16x8 vf[4];
#pragma unroll
        for (int d2 = 0; d2 < 4; ++d2) {
          int vr = d2 * 16 + c;
          int vcb = ((kk << 6) + (g << 4)) ^ ((vr & 7) << 4);
          vf[d2] = ldfrag(vsb + (((vr << 7) + vcb) >> 1));
        }
#pragma unroll
        for (int qh = 0; qh < 2; ++qh) {
          lacc[qh] = mfma16(pa_prev[qh][kk], wkf2, lacc[qh]);
#pragma unroll
          for (int d2 = 0; d2 < 4; ++d2)
            oacc[qh][d2] = mfma16(pa_prev[qh][kk], vf[d2], oacc[qh][d2]);
        }
      }
      __builtin_amdgcn_s_setprio(0);
    }

    // ---- bias + exp2 of CURRENT chunk (VALU/trans pipe) ----
    int pkmin = (int)poss[kc];
    int pkmax = (int)poss[kc + 63];
    if ((pkmin - pqmax >= 92) || (pqmin - pkmax >= 92)) {
      float rbc = (pkmin - pqmax >= 92) ? lut_hi : lut_lo;
#pragma unroll
      for (int sub = 0; sub < 4; ++sub)
#pragma unroll
        for (int qh = 0; qh < 2; ++qh)
#pragma unroll
          for (int i = 0; i < 4; ++i)
            sc[sub][qh][i] = fast_exp2(sc[sub][qh][i] + rbc);
    } else {
#pragma unroll
      for (int sub = 0; sub < 4; ++sub) {
        u16x4 pk4 = *(const u16x4*)&poss[kc + sub * 16 + (g << 2)];
#pragma unroll
        for (int qh = 0; qh < 2; ++qh)
#pragma unroll
          for (int i = 0; i < 4; ++i) {
            int idx = (int)pk4[i] + npq[qh];
            idx = idx < 0 ? 0 : (idx > 184 ? 184 : idx);
            sc[sub][qh][i] = fast_exp2(sc[sub][qh][i] + lutf[idx]);
          }
      }
    }

    // P -> PV A-frags in registers: slot 2m <- sub 2kk, slot 2m+1 <- 2kk+1
#pragma unroll
    for (int qh = 0; qh < 2; ++qh)
#pragma unroll
      for (int kk = 0; kk < 2; ++kk) {
        u32x4 pw;
#pragma unroll
        for (int m = 0; m < 4; ++m) {
          u32 pr;
          asm("v_cvt_pk_bf16_f32 %0, %1, %2"
              : "=v"(pr)
              : "v"(sc[2 * kk][qh][m]), "v"(sc[2 * kk + 1][qh][m]));
          pw[m] = pr;
        }
        pa_prev[qh][kk] = __builtin_bit_cast(bf16x8, pw);
      }
  }
#undef STAGE

  // epilogue: PV of the final chunk (31), Vs slot 31&3 = 3
  {
    const u16* vsb = Vs[31 & 3];
    const int kcp = 31 << 6;
#pragma unroll
    for (int kk = 0; kk < 2; ++kk) {
      bf16x8 wkf2 = ldfrag(wkps + kcp + kk * 32 + g * 8);
#pragma unroll
      for (int qh = 0; qh < 2; ++qh)
        lacc[qh] = mfma16(pa_prev[qh][kk], wkf2, lacc[qh]);
#pragma unroll
      for (int d2 = 0; d2 < 4; ++d2) {
        int vr = d2 * 16 + c;
        int vcb = ((kk << 6) + (g << 4)) ^ ((vr & 7) << 4);
        bf16x8 vf = ldfrag(vsb + (((vr << 7) + vcb) >> 1));
#pragma unroll
        for (int qh = 0; qh < 2; ++qh)
          oacc[qh][d2] = mfma16(pa_prev[qh][kk], vf, oacc[qh][d2]);
      }
    }
  }

#pragma unroll
  for (int qh = 0; qh < 2; ++qh)
#pragma unroll
    for (int i = 0; i < 4; ++i) {
      float iv = 1.0f / lacc[qh][i];
      int q = qrow0 + qh * 16 + (g << 2) + i;
#pragma unroll
      for (int d2 = 0; d2 < 4; ++d2)
        ctx[((size_t)b * 2048 + q) * 1024 + h * 64 + d2 * 16 + c] =
            bf16r(oacc[qh][d2][i] * iv);
    }
}

// ---------------- launch ----------------
extern "C" void kernel_launch(void* const* d_in, const int* in_sizes, int n_in,
                              void* d_out, int out_size, void* d_ws, size_t ws_size,
                              hipStream_t stream) {
  const float* hs = (const float*)d_in[0];
  const int* pos = (const int*)d_in[1];
  const float* mask = (const float*)d_in[2];
  const float* ss = (const float*)d_in[3];
  const int* nd = (const int*)d_in[4];
  const float* lnw = (const float*)d_in[5];
  const float* Wq = (const float*)d_in[6];
  const float* Wk = (const float*)d_in[7];
  const float* Wv = (const float*)d_in[8];
  const float* Wo = (const float*)d_in[9];
  const float* rel = (const float*)d_in[10];

  char* ws = (char*)d_ws;
  signed char* lut8 = (signed char*)ws;  //          0 .. 8448
  float* wkf = (float*)(ws + 8448);      //       8448 .. 24832
  u16* wkp = (u16*)(ws + 24832);         //      24832 .. 33024
  u16* normed = (u16*)(ws + 33024);      //    33024 + 8 MB (reused as ctx)
  u16* wtqkv = (u16*)(ws + 8421632);     //  + 6 MB
  u16* wto = (u16*)(ws + 14713088);      //  + 2 MB
  u16* qkv = (u16*)(ws + 16810240);      //  + 24 MB  (end 41976064)
  u16* ctx = normed;  // normed is dead after the QKV GEMM
  if (ws_size < 41976064) return;  // loud failure instead of corruption

  k_prep<<<8241, 256, 0, stream>>>(hs, lnw, normed, Wq, Wk, Wv, Wo, wtqkv,
                                   wto, mask, ss, nd, wkf, wkp, lut8);
  k_gemm<<<768, 256, 0, stream>>>(normed, wtqkv, qkv, nullptr, wkf, 0);
  k_attn<<<dim3(32, 16), 256, 0, stream>>>(qkv, pos, lut8, rel, wkp, ctx);
  k_gemm<<<256, 256, 0, stream>>>(ctx, wto, nullptr, (float*)d_out, wkf, 1);
}